// Round 1
// baseline (317.333 us; speedup 1.0000x reference)
//
#include <hip/hip_runtime.h>

// Contracter: out[z,u,k] = sum_{i,j} x1[z,u,i] * x2[z,u,j] * ww3j[u,k,i,j]
// where ww3j[u,k,i,j] = sum_p weights[u,p] * w3j[p,k,i,j].
// Z=50000, MUL=64 channels, BASE=9 (irreps 1+3+5), 11 paths. All fp32.
//
// Strategy:
//  - fold_kernel: fold per-channel path weights into dense ww (64 x 729) in d_ws.
//  - tp_kernel: one wave = one channel u (wave-uniform) x 64 consecutive z.
//    ww row (729 floats) is wave-uniform -> scalar (SMRD) loads, FMA against
//    the per-lane 81-element outer product r = x1 (x) x2. Dense 729-MAC
//    contraction: ~30us VALU total, under the ~55us HBM roofline.
//  - blockIdx swizzle: 16 blocks covering all 64 u of one z-tile are placed on
//    the same XCD (b&7) so the per-XCD L2 assembles full 2304B rows from the
//    36B-per-lane strided accesses (loads and stores).

#define MUL   64
#define BASE  9
#define NPATH 11
#define ZT    64   // z rows per tile (one per lane)

__global__ __launch_bounds__(256) void fold_kernel(
    const float* __restrict__ weights,   // (64, 11)
    const float* __restrict__ w3j,       // (11, 729)
    float*       __restrict__ ww)        // (64, 729) out
{
    int u = blockIdx.x / 3;                          // 0..63
    int t = (blockIdx.x % 3) * 256 + threadIdx.x;    // 0..767
    if (t >= 729) return;
    float acc = 0.f;
#pragma unroll
    for (int p = 0; p < NPATH; ++p)
        acc = fmaf(weights[u * NPATH + p], w3j[p * 729 + t], acc);
    ww[u * 729 + t] = acc;
}

__global__ __launch_bounds__(256) void tp_kernel(
    const float* __restrict__ x1,
    const float* __restrict__ x2,
    const float* __restrict__ ww,        // (64, 729)
    float*       __restrict__ out,
    int Z, int n_zt)
{
    // XCD-coherent swizzle: blocks b with b&7 == xcd go to (approximately) the
    // same XCD under round-robin dispatch. Group the 16 u-chunks of one z-tile
    // inside one XCD so its L2 sees the full contiguous rows.
    int b    = blockIdx.x;
    int xcd  = b & 7;
    int j    = b >> 3;
    int uc   = j & 15;        // which 4-channel chunk (4 waves/block)
    int q    = j >> 4;
    int zt   = xcd + 8 * q;   // z-tile index
    if (zt >= n_zt) return;

    int wave = threadIdx.x >> 6;
    int lane = threadIdx.x & 63;
    int u    = __builtin_amdgcn_readfirstlane(uc * 4 + wave);  // wave-uniform
    int z    = zt * ZT + lane;
    bool active = (z < Z);

    const float* __restrict__ wrow = ww + u * 729;   // uniform base -> SMRD

    const float* p1 = x1 + (size_t)z * 576 + u * 9;
    const float* p2 = x2 + (size_t)z * 576 + u * 9;

    float X1[BASE], X2[BASE];
#pragma unroll
    for (int i = 0; i < BASE; ++i) {
        X1[i] = active ? p1[i] : 0.f;
        X2[i] = active ? p2[i] : 0.f;
    }

    // 81-element outer product, per lane.
    float r[BASE * BASE];
#pragma unroll
    for (int i = 0; i < BASE; ++i)
#pragma unroll
        for (int jj = 0; jj < BASE; ++jj)
            r[i * BASE + jj] = X1[i] * X2[jj];

    // Dense contraction: o[k] = sum_t wrow[k*81+t] * r[t].
    // t-outer / k-inner gives 9 independent FMA chains (ILP).
    float o[BASE];
#pragma unroll
    for (int k = 0; k < BASE; ++k) o[k] = 0.f;
#pragma unroll
    for (int t = 0; t < BASE * BASE; ++t)
#pragma unroll
        for (int k = 0; k < BASE; ++k)
            o[k] = fmaf(wrow[k * 81 + t], r[t], o[k]);

    float* po = out + (size_t)z * 576 + u * 9;
    if (active) {
#pragma unroll
        for (int k = 0; k < BASE; ++k) po[k] = o[k];
    }
}

extern "C" void kernel_launch(void* const* d_in, const int* in_sizes, int n_in,
                              void* d_out, int out_size, void* d_ws, size_t ws_size,
                              hipStream_t stream) {
    const float* x1  = (const float*)d_in[0];
    const float* x2  = (const float*)d_in[1];
    const float* w   = (const float*)d_in[2];   // (64, 11)
    const float* w3j = (const float*)d_in[3];   // (11, 9, 9, 9)
    float* out = (float*)d_out;
    float* ww  = (float*)d_ws;                  // (64, 729) scratch, 186 KB

    int Z = in_sizes[0] / (MUL * BASE);

    // Fold weights into CG tensor: 64 channels x 3 blocks of 256 covering 729.
    fold_kernel<<<MUL * 3, 256, 0, stream>>>(w, w3j, ww);

    int n_zt = (Z + ZT - 1) / ZT;
    int Q    = (n_zt + 7) / 8;
    int grid = 8 * 16 * Q;   // xcd (8) x u-chunk (16) x q
    tp_kernel<<<grid, 256, 0, stream>>>(x1, x2, ww, out, Z, n_zt);
}